// Round 5
// baseline (290.151 us; speedup 1.0000x reference)
//
#include <hip/hip_runtime.h>
#include <hip/hip_bf16.h>
#include <math.h>

#define SEQ   168
#define BATCH 4096
#define NOUT  9
#define NBLK  256        // BATCH / 16

typedef short bf16x8 __attribute__((ext_vector_type(8)));
typedef float f32x4  __attribute__((ext_vector_type(4)));

#define MFMA(a,b,c) __builtin_amdgcn_mfma_f32_16x16x32_bf16((a),(b),(c),0,0,0)

static __device__ __forceinline__ float bf2f(unsigned short h){
    unsigned int u = ((unsigned int)h) << 16;
    return __builtin_bit_cast(float, u);
}
// hi = HW RNE convert; lo = trunc(residual) — residual captured to ~2^-16 rel
static __device__ __forceinline__ void splitf(float f, unsigned short& hi, unsigned short& lo){
    __hip_bfloat16 b = __float2bfloat16(f);
    hi = __builtin_bit_cast(unsigned short, b);
    float r = f - bf2f(hi);
    lo = (unsigned short)(__builtin_bit_cast(unsigned int, r) >> 16);
}
// clamp-free: exp->inf gives rcp=0 (correct limit)
static __device__ __forceinline__ float sigf(float x){
    return __builtin_amdgcn_rcpf(1.0f + __expf(-x));
}
// tanh(x) = 1 - 2/(1+e^{2x}); x=+inf -> 1, x=-inf -> -1, no clamps
static __device__ __forceinline__ float tanhf_(float x){
    float r = __builtin_amdgcn_rcpf(1.0f + __expf(2.0f * x));
    return fmaf(-2.0f, r, 1.0f);
}
static __device__ __forceinline__ bf16x8 ldfrag(const unsigned short* p){
    const uint4 q = *reinterpret_cast<const uint4*>(p);
    return __builtin_bit_cast(bf16x8, q);
}

// ---- pre-pass: x[S,B,24] f32 -> xw[s][blk][plane][row][k32] bf16 hi/lo planes ----
__global__ __launch_bounds__(256)
void xsplit(const float* __restrict__ x, unsigned short* __restrict__ xw)
{
    const int e     = blockIdx.x * 256 + threadIdx.x;   // flat [s][blk][plane][row][k]
    const int k     = e & 31;
    const int row   = (e >> 5) & 15;
    const int plane = (e >> 9) & 1;
    const int blk   = (e >> 10) & 255;
    const int s     = e >> 18;
    float v = 0.f;
    if (k < 24) v = x[((size_t)s * BATCH + blk * 16 + row) * 24 + k];
    unsigned short hi, lo; splitf(v, hi, lo);
    xw[e] = plane ? lo : hi;
}

// 512 threads: waves 0-3 = layer0 (step t), waves 4-7 = layer1 (step t-1) + head
// (step t-2). h planes double-buffered in MFMA A-fragment layout; 1 barrier/tick.
template<bool XW>
__global__ __launch_bounds__(512, 2)
void lstm_fused(const unsigned short* __restrict__ xw,
                const float* __restrict__ x,
                const float* __restrict__ Wih0, const float* __restrict__ Whh0,
                const float* __restrict__ bih0, const float* __restrict__ bhh0,
                const float* __restrict__ Wih1, const float* __restrict__ Whh1,
                const float* __restrict__ bih1, const float* __restrict__ bhh1,
                const float* __restrict__ Wout, const float* __restrict__ bout,
                float* __restrict__ out)
{
    __shared__ __align__(16) unsigned short sX[2][2][16][32];     // [buf][hi/lo][row][k]
    __shared__ __align__(16) unsigned short sH0H[2][16][72], sH0L[2][16][72];
    __shared__ __align__(16) unsigned short sH1H[2][16][72], sH1L[2][16][72];

    const int tid  = threadIdx.x;
    const int half = tid >> 8;        // 0: layer0 waves, 1: layer1 waves
    const int w2   = (tid >> 6) & 3;  // unit group within half
    const int l    = tid & 63;
    const int lr   = l & 15;          // A row / D col lane
    const int g    = l >> 4;          // k subgroup
    const int r0   = blockIdx.x * 16;
    const int cg   = w2 * 16 + lr;    // hidden unit [0,64)

    // ---- zero LDS (initial h,c = 0; also K-pad lanes) ----
    for (int i = tid; i < (int)(2*2*16*32/2); i += 512)
        ((unsigned int*)sX)[i] = 0u;
    for (int i = tid; i < (int)(2*16*72/2); i += 512){
        ((unsigned int*)sH0H)[i] = 0u; ((unsigned int*)sH0L)[i] = 0u;
        ((unsigned int*)sH1H)[i] = 0u; ((unsigned int*)sH1L)[i] = 0u;
    }
    __syncthreads();
    // ---- stage x_0 into buffer 0 ----
    if (XW){
        if (tid < 128){
            const uint4 v = *reinterpret_cast<const uint4*>(
                &xw[(size_t)blockIdx.x * 1024 + tid * 8]);
            *reinterpret_cast<uint4*>((char*)&sX[0][0][0][0] + tid * 16) = v;
        }
    } else {
        if (tid < 96){
            const float4 v = *reinterpret_cast<const float4*>(&x[(size_t)r0 * 24 + tid * 4]);
            const int row = (tid * 4) / 24, col = (tid * 4) % 24;
            float vv[4] = {v.x, v.y, v.z, v.w};
            #pragma unroll
            for (int j = 0; j < 4; ++j){
                unsigned short hh, ll; splitf(vv[j], hh, ll);
                sX[0][0][row][col + j] = hh; sX[0][1][row][col + j] = ll;
            }
        }
    }
    __syncthreads();

    if (half == 0){
        // ================= LAYER 0 waves =================
        bf16x8 B0H[4][3], B0L[4][3];   // ks0 = Wih0 (K=24 pad 32), ks1,2 = Whh0
        #pragma unroll
        for (int gt = 0; gt < 4; ++gt){
            const int c = gt * 64 + cg;
            bf16x8 bh = {0,0,0,0,0,0,0,0}, bl = {0,0,0,0,0,0,0,0};
            if (g < 3){
                const float* pw = &Wih0[c * 24 + g * 8];
                #pragma unroll
                for (int j = 0; j < 8; ++j){ unsigned short hh, ll; splitf(pw[j], hh, ll); bh[j]=(short)hh; bl[j]=(short)ll; }
            }
            B0H[gt][0] = bh; B0L[gt][0] = bl;
            #pragma unroll
            for (int ks = 0; ks < 2; ++ks){
                bf16x8 ch, cl;
                const float* pw = &Whh0[c * 64 + ks * 32 + g * 8];
                #pragma unroll
                for (int j = 0; j < 8; ++j){ unsigned short hh, ll; splitf(pw[j], hh, ll); ch[j]=(short)hh; cl[j]=(short)ll; }
                B0H[gt][1+ks] = ch; B0L[gt][1+ks] = cl;
            }
        }
        float b0[4];
        #pragma unroll
        for (int gt = 0; gt < 4; ++gt) b0[gt] = bih0[gt*64 + cg] + bhh0[gt*64 + cg];

        // strength-reduced x pointers (for staging x_{t+1} at tick t)
        const unsigned short* xwp = xw + (size_t)NBLK * 1024 + (size_t)blockIdx.x * 1024 + tid * 8;
        const float*          xfp = x  + ((size_t)BATCH + r0) * 24 + tid * 4;

        float c0[4] = {0,0,0,0};
        int p = 0;
        for (int t = 0; t < SEQ + 2; ++t, p ^= 1){
            if (t < SEQ){
                // issue next-x load first (latency hides under MFMA+nonlin)
                uint4  preq;
                float4 pref;
                if (XW){
                    if (tid < 128) preq = *reinterpret_cast<const uint4*>(xwp);
                } else {
                    if (tid < 96)  pref = *reinterpret_cast<const float4*>(xfp);
                }
                if (t < SEQ - 2){ xwp += (size_t)NBLK * 1024; xfp += (size_t)BATCH * 24; }

                const bf16x8 AxH = ldfrag(&sX[p][0][lr][g*8]);
                const bf16x8 AxL = ldfrag(&sX[p][1][lr][g*8]);
                bf16x8 A0H[2], A0L[2];
                #pragma unroll
                for (int ks = 0; ks < 2; ++ks){
                    A0H[ks] = ldfrag(&sH0H[p][lr][ks*32 + g*8]);
                    A0L[ks] = ldfrag(&sH0L[p][lr][ks*32 + g*8]);
                }
                f32x4 a0[4];
                #pragma unroll
                for (int gt = 0; gt < 4; ++gt){ f32x4 a = {b0[gt],b0[gt],b0[gt],b0[gt]}; a0[gt] = a; }
                __builtin_amdgcn_s_setprio(1);
                #pragma unroll
                for (int gt = 0; gt < 4; ++gt) a0[gt] = MFMA(AxH, B0H[gt][0], a0[gt]);
                #pragma unroll
                for (int gt = 0; gt < 4; ++gt) a0[gt] = MFMA(AxH, B0L[gt][0], a0[gt]);
                #pragma unroll
                for (int gt = 0; gt < 4; ++gt) a0[gt] = MFMA(AxL, B0H[gt][0], a0[gt]);
                #pragma unroll
                for (int ks = 0; ks < 2; ++ks){
                    #pragma unroll
                    for (int gt = 0; gt < 4; ++gt) a0[gt] = MFMA(A0H[ks], B0H[gt][1+ks], a0[gt]);
                    #pragma unroll
                    for (int gt = 0; gt < 4; ++gt) a0[gt] = MFMA(A0H[ks], B0L[gt][1+ks], a0[gt]);
                    #pragma unroll
                    for (int gt = 0; gt < 4; ++gt) a0[gt] = MFMA(A0L[ks], B0H[gt][1+ks], a0[gt]);
                }
                __builtin_amdgcn_s_setprio(0);
                #pragma unroll
                for (int i = 0; i < 4; ++i){
                    const int R = g * 4 + i;
                    const float ig = sigf(a0[0][i]);
                    const float fg = sigf(a0[1][i]);
                    const float gg = tanhf_(a0[2][i]);
                    const float og = sigf(a0[3][i]);
                    c0[i] = fg * c0[i] + ig * gg;
                    const float h = og * tanhf_(c0[i]);
                    unsigned short hh, ll; splitf(h, hh, ll);
                    sH0H[p ^ 1][R][cg] = hh;
                    sH0L[p ^ 1][R][cg] = ll;
                }
                // write x_{t+1} planes
                if (XW){
                    if (tid < 128)
                        *reinterpret_cast<uint4*>((char*)&sX[p ^ 1][0][0][0] + tid * 16) = preq;
                } else {
                    if (tid < 96){
                        const int row = (tid * 4) / 24, col = (tid * 4) % 24;
                        float vv[4] = {pref.x, pref.y, pref.z, pref.w};
                        #pragma unroll
                        for (int j = 0; j < 4; ++j){
                            unsigned short hh, ll; splitf(vv[j], hh, ll);
                            sX[p ^ 1][0][row][col + j] = hh; sX[p ^ 1][1][row][col + j] = ll;
                        }
                    }
                }
            }
            __syncthreads();
        }
    } else {
        // ================= LAYER 1 + head waves =================
        bf16x8 B1H[4][4], B1L[4][4];   // ks0,1 = Wih1 (h0 in), ks2,3 = Whh1 (h1 fb)
        #pragma unroll
        for (int gt = 0; gt < 4; ++gt){
            const int c = gt * 64 + cg;
            #pragma unroll
            for (int ks = 0; ks < 2; ++ks){
                bf16x8 ch, cl;
                const float* pw = &Wih1[c * 64 + ks * 32 + g * 8];
                #pragma unroll
                for (int j = 0; j < 8; ++j){ unsigned short hh, ll; splitf(pw[j], hh, ll); ch[j]=(short)hh; cl[j]=(short)ll; }
                B1H[gt][ks] = ch; B1L[gt][ks] = cl;
            }
            #pragma unroll
            for (int ks = 0; ks < 2; ++ks){
                bf16x8 ch, cl;
                const float* pw = &Whh1[c * 64 + ks * 32 + g * 8];
                #pragma unroll
                for (int j = 0; j < 8; ++j){ unsigned short hh, ll; splitf(pw[j], hh, ll); ch[j]=(short)hh; cl[j]=(short)ll; }
                B1H[gt][2+ks] = ch; B1L[gt][2+ks] = cl;
            }
        }
        const int oc = lr;             // head output column
        bf16x8 WoH[2], WoL[2];
        #pragma unroll
        for (int tt = 0; tt < 2; ++tt){
            bf16x8 bh = {0,0,0,0,0,0,0,0}, bl = {0,0,0,0,0,0,0,0};
            if (oc < NOUT){
                const float* pw = &Wout[oc * 64 + tt * 32 + g * 8];
                #pragma unroll
                for (int j = 0; j < 8; ++j){ unsigned short hh, ll; splitf(pw[j], hh, ll); bh[j]=(short)hh; bl[j]=(short)ll; }
            }
            WoH[tt] = bh; WoL[tt] = bl;
        }
        float b1[4];
        #pragma unroll
        for (int gt = 0; gt < 4; ++gt) b1[gt] = bih1[gt*64 + cg] + bhh1[gt*64 + cg];
        const float bo0 = (oc < NOUT) ? bout[oc] : 0.f;

        // strength-reduced out pointer (head at tick t writes step t-2)
        float* houtp = out + (size_t)(r0 + g * 4) * NOUT + oc;

        float c1[4] = {0,0,0,0};
        int p = 0;
        for (int t = 0; t < SEQ + 2; ++t, p ^= 1){
            if (t >= 1){
                bf16x8 A0H[2], A0L[2], A1H[2], A1L[2];
                #pragma unroll
                for (int ks = 0; ks < 2; ++ks){
                    A0H[ks] = ldfrag(&sH0H[p][lr][ks*32 + g*8]);
                    A0L[ks] = ldfrag(&sH0L[p][lr][ks*32 + g*8]);
                    A1H[ks] = ldfrag(&sH1H[p][lr][ks*32 + g*8]);
                    A1L[ks] = ldfrag(&sH1L[p][lr][ks*32 + g*8]);
                }

                // head for step t-2 (A1 frags hold h1_{t-2}), wave w2==0 only
                if (t >= 2 && w2 == 0){
                    f32x4 ha = {bo0, bo0, bo0, bo0};
                    __builtin_amdgcn_s_setprio(1);
                    #pragma unroll
                    for (int tt = 0; tt < 2; ++tt){
                        ha = MFMA(A1H[tt], WoH[tt], ha);
                        ha = MFMA(A1H[tt], WoL[tt], ha);
                        ha = MFMA(A1L[tt], WoH[tt], ha);
                    }
                    __builtin_amdgcn_s_setprio(0);
                    if (oc < NOUT){
                        #pragma unroll
                        for (int i = 0; i < 4; ++i)
                            houtp[(size_t)i * NOUT] = ha[i];
                    }
                }
                if (t >= 2) houtp += (size_t)BATCH * NOUT;

                if (t <= SEQ){
                    f32x4 a1[4];
                    #pragma unroll
                    for (int gt = 0; gt < 4; ++gt){ f32x4 a = {b1[gt],b1[gt],b1[gt],b1[gt]}; a1[gt] = a; }
                    __builtin_amdgcn_s_setprio(1);
                    #pragma unroll
                    for (int ks = 0; ks < 2; ++ks){
                        #pragma unroll
                        for (int gt = 0; gt < 4; ++gt) a1[gt] = MFMA(A0H[ks], B1H[gt][ks], a1[gt]);
                        #pragma unroll
                        for (int gt = 0; gt < 4; ++gt) a1[gt] = MFMA(A0H[ks], B1L[gt][ks], a1[gt]);
                        #pragma unroll
                        for (int gt = 0; gt < 4; ++gt) a1[gt] = MFMA(A0L[ks], B1H[gt][ks], a1[gt]);
                    }
                    #pragma unroll
                    for (int ks = 0; ks < 2; ++ks){
                        #pragma unroll
                        for (int gt = 0; gt < 4; ++gt) a1[gt] = MFMA(A1H[ks], B1H[gt][2+ks], a1[gt]);
                        #pragma unroll
                        for (int gt = 0; gt < 4; ++gt) a1[gt] = MFMA(A1H[ks], B1L[gt][2+ks], a1[gt]);
                        #pragma unroll
                        for (int gt = 0; gt < 4; ++gt) a1[gt] = MFMA(A1L[ks], B1H[gt][2+ks], a1[gt]);
                    }
                    __builtin_amdgcn_s_setprio(0);
                    #pragma unroll
                    for (int i = 0; i < 4; ++i){
                        const int R = g * 4 + i;
                        const float ig = sigf(a1[0][i]);
                        const float fg = sigf(a1[1][i]);
                        const float gg = tanhf_(a1[2][i]);
                        const float og = sigf(a1[3][i]);
                        c1[i] = fg * c1[i] + ig * gg;
                        const float h = og * tanhf_(c1[i]);
                        unsigned short hh, ll; splitf(h, hh, ll);
                        sH1H[p ^ 1][R][cg] = hh;
                        sH1L[p ^ 1][R][cg] = ll;
                    }
                }
            }
            __syncthreads();
        }
    }
}

extern "C" void kernel_launch(void* const* d_in, const int* in_sizes, int n_in,
                              void* d_out, int out_size, void* d_ws, size_t ws_size,
                              hipStream_t stream)
{
    const float* x    = (const float*)d_in[0];
    const float* Wih0 = (const float*)d_in[1];
    const float* Whh0 = (const float*)d_in[2];
    const float* bih0 = (const float*)d_in[3];
    const float* bhh0 = (const float*)d_in[4];
    const float* Wih1 = (const float*)d_in[5];
    const float* Whh1 = (const float*)d_in[6];
    const float* bih1 = (const float*)d_in[7];
    const float* bhh1 = (const float*)d_in[8];
    const float* Wout = (const float*)d_in[9];
    const float* bout = (const float*)d_in[10];
    float* out = (float*)d_out;

    const size_t need = (size_t)SEQ * NBLK * 1024 * sizeof(unsigned short); // 88 MB
    if (ws_size >= need){
        unsigned short* xw = (unsigned short*)d_ws;
        xsplit<<<SEQ * NBLK * 1024 / 256, 256, 0, stream>>>(x, xw);
        lstm_fused<true><<<NBLK, 512, 0, stream>>>(xw, x, Wih0, Whh0, bih0, bhh0,
                                                   Wih1, Whh1, bih1, bhh1,
                                                   Wout, bout, out);
    } else {
        lstm_fused<false><<<NBLK, 512, 0, stream>>>(nullptr, x, Wih0, Whh0, bih0, bhh0,
                                                    Wih1, Whh1, bih1, bhh1,
                                                    Wout, bout, out);
    }
}

// Round 6
// 232.367 us; speedup vs baseline: 1.2487x; 1.2487x over previous
//
#include <hip/hip_runtime.h>
#include <hip/hip_bf16.h>
#include <math.h>

#define SEQ   168
#define BATCH 4096
#define NOUT  9
#define NBLK  256        // BATCH / 16

typedef short bf16x8 __attribute__((ext_vector_type(8)));
typedef float f32x4  __attribute__((ext_vector_type(4)));

#define MFMA(a,b,c) __builtin_amdgcn_mfma_f32_16x16x32_bf16((a),(b),(c),0,0,0)

static __device__ __forceinline__ float bf2f(unsigned short h){
    unsigned int u = ((unsigned int)h) << 16;
    return __builtin_bit_cast(float, u);
}
// hi = HW RNE convert; lo = trunc(residual)
static __device__ __forceinline__ void splitf(float f, unsigned short& hi, unsigned short& lo){
    __hip_bfloat16 b = __float2bfloat16(f);
    hi = __builtin_bit_cast(unsigned short, b);
    float r = f - bf2f(hi);
    lo = (unsigned short)(__builtin_bit_cast(unsigned int, r) >> 16);
}
// clamp-free: exp->inf gives rcp=0 (correct limit)
static __device__ __forceinline__ float sigf(float x){
    return __builtin_amdgcn_rcpf(1.0f + __expf(-x));
}
// tanh(x) = 1 - 2/(1+e^{2x}); +/-inf -> +/-1, no clamps
static __device__ __forceinline__ float tanhf_(float x){
    float r = __builtin_amdgcn_rcpf(1.0f + __expf(2.0f * x));
    return fmaf(-2.0f, r, 1.0f);
}
static __device__ __forceinline__ bf16x8 ldfrag(const unsigned short* p){
    const uint4 q = *reinterpret_cast<const uint4*>(p);
    return __builtin_bit_cast(bf16x8, q);
}

// group-local sense-reversing barrier over 4 waves; last arriver posts `tickval`
// to the cross-group counter and flips the phase (release).
static __device__ __forceinline__ void gbar(int* cnt, int* phs, int* done,
                                            int tickval, int& ph, int lane){
    asm volatile("s_waitcnt lgkmcnt(0)" ::: "memory");   // own ds writes visible
    if (lane == 0){
        int old = __hip_atomic_fetch_add(cnt, 1, __ATOMIC_ACQ_REL,
                                         __HIP_MEMORY_SCOPE_WORKGROUP);
        if (old == 3){
            *cnt = 0;
            __hip_atomic_store(done, tickval, __ATOMIC_RELEASE,
                               __HIP_MEMORY_SCOPE_WORKGROUP);
            __hip_atomic_store(phs, ph ^ 1, __ATOMIC_RELEASE,
                               __HIP_MEMORY_SCOPE_WORKGROUP);
        }
    }
    while (__hip_atomic_load(phs, __ATOMIC_ACQUIRE,
                             __HIP_MEMORY_SCOPE_WORKGROUP) == ph)
        __builtin_amdgcn_s_sleep(1);
    ph ^= 1;
}
static __device__ __forceinline__ void wait_ge(int* done, int need){
    while (__hip_atomic_load(done, __ATOMIC_ACQUIRE,
                             __HIP_MEMORY_SCOPE_WORKGROUP) < need)
        __builtin_amdgcn_s_sleep(1);
}

// 512 threads. Waves 0-3: layer0 tick t in [0,SEQ). Waves 4-7: layer1 tick t in
// [1,SEQ+1] (step t-1) + head (step t-2). Groups sync independently; cross-group
// producer/consumer via LDS tick counters -> up to one tick of skew, so the two
// waves sharing a SIMD run de-phased (MFMA of one overlaps trans/VALU of other).
__global__ __launch_bounds__(512, 2)
void lstm_fused(const float* __restrict__ x,
                const float* __restrict__ Wih0, const float* __restrict__ Whh0,
                const float* __restrict__ bih0, const float* __restrict__ bhh0,
                const float* __restrict__ Wih1, const float* __restrict__ Whh1,
                const float* __restrict__ bih1, const float* __restrict__ bhh1,
                const float* __restrict__ Wout, const float* __restrict__ bout,
                float* __restrict__ out)
{
    __shared__ __align__(16) unsigned short sXH[2][16][40],  sXL[2][16][40];
    __shared__ __align__(16) unsigned short sH0H[2][16][72], sH0L[2][16][72];
    __shared__ __align__(16) unsigned short sH1H[2][16][72], sH1L[2][16][72];
    __shared__ int sync[8];  // [0,1]=cnt, [2,3]=phase, [4]=l0_done, [5]=l1_done

    const int tid  = threadIdx.x;
    const int half = tid >> 8;        // 0: layer0 waves, 1: layer1 waves
    const int w2   = (tid >> 6) & 3;  // unit group within half
    const int l    = tid & 63;
    const int lr   = l & 15;          // A row / D col lane
    const int g    = l >> 4;          // k subgroup
    const int r0   = blockIdx.x * 16;
    const int cg   = w2 * 16 + lr;    // hidden unit [0,64)

    if (tid < 8) sync[tid] = (tid == 4) ? -1 : 0;

    // ---- zero LDS (initial h,c = 0; also K-pad lanes) ----
    for (int i = tid; i < (int)(2*16*40/2); i += 512){
        ((unsigned int*)sXH)[i] = 0u; ((unsigned int*)sXL)[i] = 0u;
    }
    for (int i = tid; i < (int)(2*16*72/2); i += 512){
        ((unsigned int*)sH0H)[i] = 0u; ((unsigned int*)sH0L)[i] = 0u;
        ((unsigned int*)sH1H)[i] = 0u; ((unsigned int*)sH1L)[i] = 0u;
    }
    __syncthreads();
    // ---- stage x_0 into buffer 0 ----
    if (tid < 96){
        const float4 v = *reinterpret_cast<const float4*>(&x[(size_t)r0 * 24 + tid * 4]);
        const int row = (tid * 4) / 24, col = (tid * 4) % 24;
        float vv[4] = {v.x, v.y, v.z, v.w};
        #pragma unroll
        for (int j = 0; j < 4; ++j){
            unsigned short hh, ll; splitf(vv[j], hh, ll);
            sXH[0][row][col + j] = hh; sXL[0][row][col + j] = ll;
        }
    }
    __syncthreads();

    if (half == 0){
        // ================= LAYER 0 waves (group 0) =================
        bf16x8 B0H[4][3], B0L[4][3];   // ks0 = Wih0 (K=24 pad 32), ks1,2 = Whh0
        #pragma unroll
        for (int gt = 0; gt < 4; ++gt){
            const int c = gt * 64 + cg;
            bf16x8 bh = {0,0,0,0,0,0,0,0}, bl = {0,0,0,0,0,0,0,0};
            if (g < 3){
                const float* pw = &Wih0[c * 24 + g * 8];
                #pragma unroll
                for (int j = 0; j < 8; ++j){ unsigned short hh, ll; splitf(pw[j], hh, ll); bh[j]=(short)hh; bl[j]=(short)ll; }
            }
            B0H[gt][0] = bh; B0L[gt][0] = bl;
            #pragma unroll
            for (int ks = 0; ks < 2; ++ks){
                bf16x8 ch, cl;
                const float* pw = &Whh0[c * 64 + ks * 32 + g * 8];
                #pragma unroll
                for (int j = 0; j < 8; ++j){ unsigned short hh, ll; splitf(pw[j], hh, ll); ch[j]=(short)hh; cl[j]=(short)ll; }
                B0H[gt][1+ks] = ch; B0L[gt][1+ks] = cl;
            }
        }
        float b0[4];
        #pragma unroll
        for (int gt = 0; gt < 4; ++gt) b0[gt] = bih0[gt*64 + cg] + bhh0[gt*64 + cg];

        const float* xfp = x + ((size_t)BATCH + r0) * 24 + tid * 4;  // x for tick t+1
        float c0[4] = {0,0,0,0};
        int ph = 0;
        for (int t = 0; t < SEQ; ++t){
            const int p = t & 1;
            // prefetch next x tile early (hides under MFMA)
            const bool ldx = (tid < 96) && (t + 1 < SEQ);
            float4 pref;
            if (ldx){ pref = *reinterpret_cast<const float4*>(xfp); xfp += (size_t)BATCH * 24; }

            const bf16x8 AxH = ldfrag(&sXH[p][lr][g*8]);
            const bf16x8 AxL = ldfrag(&sXL[p][lr][g*8]);
            bf16x8 A0H[2], A0L[2];
            #pragma unroll
            for (int ks = 0; ks < 2; ++ks){
                A0H[ks] = ldfrag(&sH0H[p][lr][ks*32 + g*8]);
                A0L[ks] = ldfrag(&sH0L[p][lr][ks*32 + g*8]);
            }
            f32x4 a0[4];
            #pragma unroll
            for (int gt = 0; gt < 4; ++gt){ f32x4 a = {b0[gt],b0[gt],b0[gt],b0[gt]}; a0[gt] = a; }
            #pragma unroll
            for (int gt = 0; gt < 4; ++gt) a0[gt] = MFMA(AxH, B0H[gt][0], a0[gt]);
            #pragma unroll
            for (int gt = 0; gt < 4; ++gt) a0[gt] = MFMA(AxH, B0L[gt][0], a0[gt]);
            #pragma unroll
            for (int gt = 0; gt < 4; ++gt) a0[gt] = MFMA(AxL, B0H[gt][0], a0[gt]);
            #pragma unroll
            for (int ks = 0; ks < 2; ++ks){
                #pragma unroll
                for (int gt = 0; gt < 4; ++gt) a0[gt] = MFMA(A0H[ks], B0H[gt][1+ks], a0[gt]);
                #pragma unroll
                for (int gt = 0; gt < 4; ++gt) a0[gt] = MFMA(A0H[ks], B0L[gt][1+ks], a0[gt]);
                #pragma unroll
                for (int gt = 0; gt < 4; ++gt) a0[gt] = MFMA(A0L[ks], B0H[gt][1+ks], a0[gt]);
            }
            // nonlinearity into regs
            unsigned short hh[4], llo[4];
            #pragma unroll
            for (int i = 0; i < 4; ++i){
                const float ig = sigf(a0[0][i]);
                const float fg = sigf(a0[1][i]);
                const float gg = tanhf_(a0[2][i]);
                const float og = sigf(a0[3][i]);
                c0[i] = fg * c0[i] + ig * gg;
                const float h = og * tanhf_(c0[i]);
                splitf(h, hh[i], llo[i]);
            }
            // before overwriting h0[p^1]: l1 must have consumed it (its tick t-1)
            if (t >= 2) wait_ge(&sync[5], t - 1);
            #pragma unroll
            for (int i = 0; i < 4; ++i){
                const int R = g * 4 + i;
                sH0H[p ^ 1][R][cg] = hh[i];
                sH0L[p ^ 1][R][cg] = llo[i];
            }
            if (ldx){
                const int row = (tid * 4) / 24, col = (tid * 4) % 24;
                float vv[4] = {pref.x, pref.y, pref.z, pref.w};
                #pragma unroll
                for (int j = 0; j < 4; ++j){
                    unsigned short ah, al; splitf(vv[j], ah, al);
                    sXH[p ^ 1][row][col + j] = ah; sXL[p ^ 1][row][col + j] = al;
                }
            }
            gbar(&sync[0], &sync[2], &sync[4], t, ph, l);
        }
    } else {
        // ================= LAYER 1 + head waves (group 1) =================
        bf16x8 B1H[4][4], B1L[4][4];   // ks0,1 = Wih1 (h0 in), ks2,3 = Whh1 (h1 fb)
        #pragma unroll
        for (int gt = 0; gt < 4; ++gt){
            const int c = gt * 64 + cg;
            #pragma unroll
            for (int ks = 0; ks < 2; ++ks){
                bf16x8 ch, cl;
                const float* pw = &Wih1[c * 64 + ks * 32 + g * 8];
                #pragma unroll
                for (int j = 0; j < 8; ++j){ unsigned short hh, ll; splitf(pw[j], hh, ll); ch[j]=(short)hh; cl[j]=(short)ll; }
                B1H[gt][ks] = ch; B1L[gt][ks] = cl;
            }
            #pragma unroll
            for (int ks = 0; ks < 2; ++ks){
                bf16x8 ch, cl;
                const float* pw = &Whh1[c * 64 + ks * 32 + g * 8];
                #pragma unroll
                for (int j = 0; j < 8; ++j){ unsigned short hh, ll; splitf(pw[j], hh, ll); ch[j]=(short)hh; cl[j]=(short)ll; }
                B1H[gt][2+ks] = ch; B1L[gt][2+ks] = cl;
            }
        }
        const int oc = lr;             // head output column
        bf16x8 WoH[2], WoL[2];
        #pragma unroll
        for (int tt = 0; tt < 2; ++tt){
            bf16x8 bh = {0,0,0,0,0,0,0,0}, bl = {0,0,0,0,0,0,0,0};
            if (oc < NOUT){
                const float* pw = &Wout[oc * 64 + tt * 32 + g * 8];
                #pragma unroll
                for (int j = 0; j < 8; ++j){ unsigned short hh, ll; splitf(pw[j], hh, ll); bh[j]=(short)hh; bl[j]=(short)ll; }
            }
            WoH[tt] = bh; WoL[tt] = bl;
        }
        float b1[4];
        #pragma unroll
        for (int gt = 0; gt < 4; ++gt) b1[gt] = bih1[gt*64 + cg] + bhh1[gt*64 + cg];
        const float bo0 = (oc < NOUT) ? bout[oc] : 0.f;

        float* houtp = out + (size_t)(r0 + g * 4) * NOUT + oc;
        float c1[4] = {0,0,0,0};
        int ph = 0;
        for (int t = 1; t <= SEQ + 1; ++t){
            const int p = t & 1;
            // own-group reads first: h1 feedback frags (also feed the head)
            bf16x8 A1H[2], A1L[2];
            #pragma unroll
            for (int ks = 0; ks < 2; ++ks){
                A1H[ks] = ldfrag(&sH1H[p][lr][ks*32 + g*8]);
                A1L[ks] = ldfrag(&sH1L[p][lr][ks*32 + g*8]);
            }
            // head for step t-2 — overlaps l0's production of h0(t-1)
            if (t >= 2 && w2 == 0){
                f32x4 ha = {bo0, bo0, bo0, bo0};
                #pragma unroll
                for (int tt = 0; tt < 2; ++tt){
                    ha = MFMA(A1H[tt], WoH[tt], ha);
                    ha = MFMA(A1H[tt], WoL[tt], ha);
                    ha = MFMA(A1L[tt], WoH[tt], ha);
                }
                if (oc < NOUT){
                    #pragma unroll
                    for (int i = 0; i < 4; ++i)
                        houtp[(size_t)i * NOUT] = ha[i];
                }
            }
            if (t >= 2) houtp += (size_t)BATCH * NOUT;

            // wait for h0(t-1) from layer-0 group
            const int need = (t - 1 < SEQ - 1) ? (t - 1) : (SEQ - 1);
            wait_ge(&sync[4], need);

            if (t <= SEQ){
                bf16x8 A0H[2], A0L[2];
                #pragma unroll
                for (int ks = 0; ks < 2; ++ks){
                    A0H[ks] = ldfrag(&sH0H[p][lr][ks*32 + g*8]);
                    A0L[ks] = ldfrag(&sH0L[p][lr][ks*32 + g*8]);
                }
                f32x4 a1[4];
                #pragma unroll
                for (int gt = 0; gt < 4; ++gt){ f32x4 a = {b1[gt],b1[gt],b1[gt],b1[gt]}; a1[gt] = a; }
                #pragma unroll
                for (int ks = 0; ks < 2; ++ks){
                    #pragma unroll
                    for (int gt = 0; gt < 4; ++gt) a1[gt] = MFMA(A0H[ks], B1H[gt][ks], a1[gt]);
                    #pragma unroll
                    for (int gt = 0; gt < 4; ++gt) a1[gt] = MFMA(A0H[ks], B1L[gt][ks], a1[gt]);
                    #pragma unroll
                    for (int gt = 0; gt < 4; ++gt) a1[gt] = MFMA(A0L[ks], B1H[gt][ks], a1[gt]);
                }
                #pragma unroll
                for (int ks = 0; ks < 2; ++ks){
                    #pragma unroll
                    for (int gt = 0; gt < 4; ++gt) a1[gt] = MFMA(A1H[ks], B1H[gt][2+ks], a1[gt]);
                    #pragma unroll
                    for (int gt = 0; gt < 4; ++gt) a1[gt] = MFMA(A1H[ks], B1L[gt][2+ks], a1[gt]);
                    #pragma unroll
                    for (int gt = 0; gt < 4; ++gt) a1[gt] = MFMA(A1L[ks], B1H[gt][2+ks], a1[gt]);
                }
                #pragma unroll
                for (int i = 0; i < 4; ++i){
                    const int R = g * 4 + i;
                    const float ig = sigf(a1[0][i]);
                    const float fg = sigf(a1[1][i]);
                    const float gg = tanhf_(a1[2][i]);
                    const float og = sigf(a1[3][i]);
                    c1[i] = fg * c1[i] + ig * gg;
                    const float h = og * tanhf_(c1[i]);
                    unsigned short hh, ll; splitf(h, hh, ll);
                    sH1H[p ^ 1][R][cg] = hh;
                    sH1L[p ^ 1][R][cg] = ll;
                }
            }
            gbar(&sync[1], &sync[3], &sync[5], t, ph, l);
        }
    }
}

extern "C" void kernel_launch(void* const* d_in, const int* in_sizes, int n_in,
                              void* d_out, int out_size, void* d_ws, size_t ws_size,
                              hipStream_t stream)
{
    const float* x    = (const float*)d_in[0];
    const float* Wih0 = (const float*)d_in[1];
    const float* Whh0 = (const float*)d_in[2];
    const float* bih0 = (const float*)d_in[3];
    const float* bhh0 = (const float*)d_in[4];
    const float* Wih1 = (const float*)d_in[5];
    const float* Whh1 = (const float*)d_in[6];
    const float* bih1 = (const float*)d_in[7];
    const float* bhh1 = (const float*)d_in[8];
    const float* Wout = (const float*)d_in[9];
    const float* bout = (const float*)d_in[10];
    float* out = (float*)d_out;

    lstm_fused<<<NBLK, 512, 0, stream>>>(x, Wih0, Whh0, bih0, bhh0,
                                         Wih1, Whh1, bih1, bhh1,
                                         Wout, bout, out);
}